// Round 2
// baseline (485.356 us; speedup 1.0000x reference)
//
#include <hip/hip_runtime.h>
#include <hip/hip_cooperative_groups.h>
#include <math.h>

namespace cg = cooperative_groups;

#define B_ 2
#define S_ 128
#define H_ 4
#define DK_ 128
#define NB_ 4
#define D_ 512
#define M_ 256   // B_*S_

typedef __attribute__((ext_vector_type(8))) short short8;
typedef __attribute__((ext_vector_type(4))) float float4v;
typedef __attribute__((ext_vector_type(4))) unsigned short ushort4v;

__device__ __forceinline__ float elu1(float x) {
    return (x > 0.f) ? (x + 1.f) : __expf(x);
}

__device__ __forceinline__ unsigned short f2bf(float f) {
    unsigned u = __float_as_uint(f);
    unsigned r = (u + 0x7FFFu + ((u >> 16) & 1u)) >> 16;
    return (unsigned short)r;
}

// ---------------------------------------------------------------------------
// ws layout (float offsets) — identical to prior rounds
// ---------------------------------------------------------------------------

struct MegaArgs {
    const float *x_m, *x_c, *b_m, *b_c, *bb_m, *bb_c, *p_m, *p_c;
    const float *W_xm, *W_xc, *W_bm, *W_bc;
    const float *Wq1_b, *Wq2_w, *Wq2_b, *Wk1_b, *Wk2_w, *Wk2_b;
    const float *Wq1_w, *Wk1_w;
    const float *mean_w, *mean_b, *cov_w, *cov_b, *ln_w, *ln_b;
    const int *b_seq;
    float *qkv, *pq, *pk, *bbq, *bbk, *fKm, *fKs, *y_m, *y_c;
    unsigned short *A_m, *A_c, *Wt, *wm_bf, *wc_bf, *mctxb, *cctxb, *pm_bf, *bbm_bf, *w4_bf;
    float *out;
};

// ===========================================================================
// MEGA KERNEL: all 6 phases, one launch, grid.sync() between phases.
// 512 blocks x 256 threads (co-resident: ~10.6KB LDS, modest VGPR).
// Each phase body is verbatim from the 6-kernel pipeline (bitwise-identical
// per-element math); only work->block index mappings changed.
// ===========================================================================
__global__ __launch_bounds__(256) void k_mega(MegaArgs P)
{
    cg::grid_group gg = cg::this_grid();
    __shared__ __attribute__((aligned(16))) float smemf[2640];   // 10560 B overlay
    const int t = threadIdx.x;
    const int blk = blockIdx.x;   // 0..511

    // ---------------- P1: bf16 conversions (grid-stride) ----------------
    for (int cid = blk * 256 + t; cid < 315392; cid += 131072) {
        const float* srcp;
        unsigned short* dstp;
        if (cid < 262144) {
            int job = cid >> 16;
            int off = (cid & 65535) * 4;
            if (job <= 1) {
                int m = off >> 10, k = off & 1023;
                if (job == 0) { srcp = (k < 512) ? (P.x_m + m * 512 + k) : (P.b_m + m * 512 + k - 512); dstp = P.A_m + off; }
                else          { srcp = (k < 512) ? (P.x_c + m * 512 + k) : (P.b_c + m * 512 + k - 512); dstp = P.A_c + off; }
            } else if (job == 2) { srcp = P.mean_w + off; dstp = P.wm_bf + off; }
            else                 { srcp = P.cov_w + off;  dstp = P.wc_bf + off; }
        } else if (cid < 294912) {
            int off = (cid - 262144) * 4;
            srcp = P.p_m + off; dstp = P.pm_bf + off;
        } else if (cid < 299008) {
            int off = (cid - 294912) * 4;
            srcp = P.bb_m + off; dstp = P.bbm_bf + off;
        } else {
            int off = (cid - 299008) * 4;
            int seg = off >> 14;
            const float* Ws = (seg == 0) ? P.Wq2_w : (seg == 1) ? P.Wk2_w : (seg == 2) ? P.Wq1_w : P.Wk1_w;
            srcp = Ws + (off & 16383); dstp = P.w4_bf + off;
        }
        float4 v = *(const float4*)srcp;
        ushort4v o4;
        o4.x = f2bf(v.x); o4.y = f2bf(v.y); o4.z = f2bf(v.z); o4.w = f2bf(v.w);
        *(ushort4v*)dstp = o4;
    }

    // ---------------- P1b: projection-weight transpose (3072 tiles, 6/block) ----
    {
        unsigned short (*tile2)[32][33] = reinterpret_cast<unsigned short(*)[32][33]>(smemf);
        const int tx = t & 31, ty = t >> 5;
        for (int batch = 0; batch < 3; ++batch) {
            __syncthreads();
#pragma unroll
            for (int it = 0; it < 2; ++it) {
                const int tid = blk + (batch * 2 + it) * 512;
                const int nt = tid & 15, kt = (tid >> 4) & 15, z = tid >> 8;
                const int o = z >> 1, part = z & 1;
                const float* src = (part == 0)
                    ? ((o < 3) ? (P.W_xm + o * 262144) : (P.W_xc + (o - 3) * 262144))
                    : ((o < 3) ? (P.W_bm + o * 262144) : (P.W_bc + (o - 3) * 262144));
#pragma unroll
                for (int u = 0; u < 4; ++u)
                    tile2[it][ty + u * 8][tx] = f2bf(src[(kt * 32 + ty + u * 8) * 512 + nt * 32 + tx]);
            }
            __syncthreads();
#pragma unroll
            for (int it = 0; it < 2; ++it) {
                const int tid = blk + (batch * 2 + it) * 512;
                const int nt = tid & 15, kt = (tid >> 4) & 15, z = tid >> 8;
                const int o = z >> 1, part = z & 1;
                unsigned short* dst = P.Wt + o * 524288 + part * 512;
#pragma unroll
                for (int u = 0; u < 4; ++u)
                    dst[(nt * 32 + ty + u * 8) * 1024 + kt * 32 + tx] = tile2[it][tx][ty + u * 8];
            }
        }
    }
    gg.sync();

    // ---------------- P2: MFMA GEMMs (2688 wave-jobs over 2048 waves) ----------
    {
        const int lane = t & 63;
        const int l15 = lane & 15, quad = lane >> 4;
        for (int wid = blk * 4 + (t >> 6); wid < 2688; wid += 2048) {
            if (wid < 1536) {
                const int o = wid >> 8;
                const int rem = wid & 255;
                const int nt2 = rem & 15, mt = rem >> 4;
                const int m0 = mt * 16, n0 = nt2 * 32;

                const unsigned short* Abf = (o < 3) ? P.A_m : P.A_c;
                const unsigned short* ap  = Abf + (m0 + l15) * 1024 + quad * 8;
                const unsigned short* bpa = P.Wt + o * 524288 + (n0 + l15) * 1024 + quad * 8;
                const unsigned short* bpb = bpa + 16 * 1024;

                float4v accA0 = {0.f, 0.f, 0.f, 0.f};
                float4v accA1 = {0.f, 0.f, 0.f, 0.f};
                float4v accB0 = {0.f, 0.f, 0.f, 0.f};
                float4v accB1 = {0.f, 0.f, 0.f, 0.f};
#pragma unroll
                for (int k0 = 0; k0 < 1024; k0 += 64) {
                    short8 a0 = *(const short8*)(ap + k0);
                    short8 a1 = *(const short8*)(ap + k0 + 32);
                    short8 b0a = *(const short8*)(bpa + k0);
                    short8 b1a = *(const short8*)(bpa + k0 + 32);
                    short8 b0b = *(const short8*)(bpb + k0);
                    short8 b1b = *(const short8*)(bpb + k0 + 32);
                    accA0 = __builtin_amdgcn_mfma_f32_16x16x32_bf16(a0, b0a, accA0, 0, 0, 0);
                    accA1 = __builtin_amdgcn_mfma_f32_16x16x32_bf16(a1, b1a, accA1, 0, 0, 0);
                    accB0 = __builtin_amdgcn_mfma_f32_16x16x32_bf16(a0, b0b, accB0, 0, 0, 0);
                    accB1 = __builtin_amdgcn_mfma_f32_16x16x32_bf16(a1, b1b, accB1, 0, 0, 0);
                }
                float* dst = P.qkv + o * 131072;
#pragma unroll
                for (int r = 0; r < 4; ++r) {
                    float va = accA0[r] + accA1[r];
                    float vb = accB0[r] + accB1[r];
                    if (o >= 3) { va = elu1(va); vb = elu1(vb); }
                    dst[(m0 + quad * 4 + r) * 512 + n0 + l15] = va;
                    dst[(m0 + quad * 4 + r) * 512 + n0 + 16 + l15] = vb;
                }
            } else {
                const unsigned short* Abf;
                const unsigned short* Wb;
                const float* bias;
                float* dst;
                int m0, n0, h;
                if (wid < 2560) {
                    int lid = wid - 1536;
                    int sel = lid >> 9;              // 0=pq(Wq2), 1=pk(Wk2)
                    int r = lid & 511;
                    h = r >> 7;
                    int rem = r & 127;
                    m0 = (rem >> 3) * 16; n0 = (rem & 7) * 16;
                    Abf = P.pm_bf;
                    Wb = P.w4_bf + sel * 16384;
                    bias = sel ? P.Wk2_b : P.Wq2_b;
                    dst = sel ? P.pk : P.pq;
                } else {
                    int lid = wid - 2560;
                    int sel = lid >> 6;              // 0=bbq(Wq1), 1=bbk(Wk1)
                    int r = lid & 63;
                    h = r >> 4;
                    int rem = r & 15;
                    m0 = (rem >> 3) * 16; n0 = (rem & 7) * 16;
                    Abf = P.bbm_bf;
                    Wb = P.w4_bf + 32768 + sel * 16384;
                    bias = sel ? P.Wk1_b : P.Wq1_b;
                    dst = sel ? P.bbk : P.bbq;
                }
                const unsigned short* ap = Abf + (m0 + l15) * 512 + h * 128 + quad * 8;
                const unsigned short* bp = Wb + (n0 + l15) * 128 + quad * 8;

                float4v acc0 = {0.f, 0.f, 0.f, 0.f};
                float4v acc1 = {0.f, 0.f, 0.f, 0.f};
#pragma unroll
                for (int k0 = 0; k0 < 128; k0 += 64) {
                    short8 a0 = *(const short8*)(ap + k0);
                    short8 b0 = *(const short8*)(bp + k0);
                    short8 a1 = *(const short8*)(ap + k0 + 32);
                    short8 b1 = *(const short8*)(bp + k0 + 32);
                    acc0 = __builtin_amdgcn_mfma_f32_16x16x32_bf16(a0, b0, acc0, 0, 0, 0);
                    acc1 = __builtin_amdgcn_mfma_f32_16x16x32_bf16(a1, b1, acc1, 0, 0, 0);
                }
                float bv = bias[n0 + l15];
#pragma unroll
                for (int r = 0; r < 4; ++r)
                    dst[(m0 + quad * 4 + r) * 512 + h * 128 + n0 + l15] = acc0[r] + acc1[r] + bv;
            }
        }
    }
    gg.sync();

    // ---------------- P3: fuseK (1024 units of 128 threads) ----------------
    {
        const int half = t >> 7, tl = t & 127;
        const int u = blk * 2 + half;            // 0..1023
        const int j = u & 127, h = (u >> 7) & 3, b = u >> 9;
        const float eps = 1e-24f;
        const int d = h * 128 + tl;
        const int base = (b * S_ + j) * D_ + d;
        const int sj = P.b_seq[b * S_ + j];

        float m1 = P.qkv[M_ * D_ + base];        // k1
        float c1 = P.qkv[4 * M_ * D_ + base];    // k2 (elu'd)
        float m3 = P.pk[base];
        float c3 = P.p_c[base];

        float p1 = 1.f / fmaxf(c1, eps);
        float p3 = 1.f / fmaxf(c3, eps);
        float mp13 = m1 * p1 + m3 * p3;

#pragma unroll
        for (int sv = 0; sv < 4; ++sv) {
            int idx = (b * 16 + sj * 4 + sv) * 512 + d;
            float m2 = P.bbk[idx];
            float c2 = P.bb_c[idx];
            float p2 = 1.f / fmaxf(c2, eps);
            float cc = 1.f / (p1 + p2 + p3);
            int o = (((b * H_ + h) * 4 + sv) * S_ + j) * 128 + tl;
            P.fKm[o] = cc * (mp13 + m2 * p2);
            P.fKs[o] = sqrtf(fmaxf(cc, eps));
        }
    }
    gg.sync();

    // ---------------- P4: attn (1024 units of 128 threads, 2 per block) --------
    {
        const int half = t >> 7, tl = t & 127;
        const int u = blk * 2 + half;            // 0..1023
        const int i = u & 127, h = (u >> 7) & 3, b = u >> 9;
        const float eps = 1e-24f;

        float* qm  = smemf + half * 528;          // [2][4*132]
        float* qs  = smemf + 1056 + half * 528;
        float* pr  = smemf + 2112 + half * 128;
        float* pr2 = smemf + 2368 + half * 128;
        float* red = smemf + 2624 + half * 4;

        const int si = P.b_seq[b * S_ + i];
        const int sj = P.b_seq[b * S_ + tl];

        {
            const int d = h * 128 + tl;
            const int base = (b * S_ + i) * D_ + d;
            float m1 = P.qkv[base];                  // q1
            float c1 = P.qkv[3 * M_ * D_ + base];    // q2 (elu'd)
            float m3 = P.pq[base];
            float c3 = P.p_c[base];
            float p1 = 1.f / fmaxf(c1, eps);
            float p3 = 1.f / fmaxf(c3, eps);
            float mp13 = m1 * p1 + m3 * p3;
#pragma unroll
            for (int sv = 0; sv < 4; ++sv) {
                int idx = (b * 16 + sv * 4 + si) * 512 + d;
                float m2 = P.bbq[idx];
                float c2 = P.bb_c[idx];
                float p2 = 1.f / fmaxf(c2, eps);
                float cc = 1.f / (p1 + p2 + p3);
                qm[sv * 132 + tl] = cc * (mp13 + m2 * p2);
                qs[sv * 132 + tl] = sqrtf(fmaxf(cc, eps));
            }
        }
        __syncthreads();

        const int krow = (((b * H_ + h) * 4 + si) * S_ + tl) * 128;
        const float4* kmp = (const float4*)(P.fKm + krow);
        const float4* ksp = (const float4*)(P.fKs + krow);

        float w2 = 0.f;
#pragma unroll 4
        for (int k4 = 0; k4 < 32; ++k4) {
            float4 km = kmp[k4];
            float4 ks = ksp[k4];
            float4 m = *(const float4*)&qm[sj * 132 + k4 * 4];
            float4 s = *(const float4*)&qs[sj * 132 + k4 * 4];
            float d0 = m.x - km.x, d1 = m.y - km.y, d2 = m.z - km.z, d3 = m.w - km.w;
            float e0 = s.x - ks.x, e1 = s.y - ks.y, e2 = s.z - ks.z, e3 = s.w - ks.w;
            w2 += d0 * d0 + d1 * d1 + d2 * d2 + d3 * d3
                + e0 * e0 + e1 * e1 + e2 * e2 + e3 * e3;
        }
        float score = -w2 * 0.08838834764831845f;   // 1/sqrt(128)

        float mx = score;
#pragma unroll
        for (int off = 32; off >= 1; off >>= 1) mx = fmaxf(mx, __shfl_xor(mx, off));
        if ((tl & 63) == 0) red[tl >> 6] = mx;
        __syncthreads();
        mx = fmaxf(red[0], red[1]);
        float e = __expf(score - mx);
        float sm = e;
#pragma unroll
        for (int off = 32; off >= 1; off >>= 1) sm += __shfl_xor(sm, off);
        if ((tl & 63) == 0) red[2 + (tl >> 6)] = sm;
        __syncthreads();
        float p = e / (red[2] + red[3]);

        P.out[262144 + ((b * H_ + h) * S_ + i) * S_ + tl] = p;
        pr[tl] = p;
        pr2[tl] = p * p;
        __syncthreads();

        const float* v1 = P.qkv + 2 * M_ * D_ + (b * S_) * D_ + h * 128 + tl;
        const float* v2 = P.qkv + 5 * M_ * D_ + (b * S_) * D_ + h * 128 + tl;
        float am = 0.f, ac = 0.f;
#pragma unroll 8
        for (int j = 0; j < 128; ++j) {
            am = fmaf(pr[j], v1[j * D_], am);
            ac = fmaf(pr2[j], v2[j * D_], ac);
        }
        P.mctxb[(b * S_ + i) * D_ + h * 128 + tl] = f2bf(am);
        P.cctxb[(b * S_ + i) * D_ + h * 128 + tl] = f2bf(ac);
    }
    gg.sync();

    // ---------------- P5a: epilogue MFMA GEMM (1024 wave-jobs) ----------------
    {
        const int lane = t & 63;
        const int l15 = lane & 15, quad = lane >> 4;
        const int wid = blk * 4 + (t >> 6);
        if (wid < 1024) {
            const int mat = wid >> 9;
            const int rem = wid & 511;
            const int nt = rem & 31, mt = rem >> 5;
            const int m0 = mt * 16, n0 = nt * 16;

            const unsigned short* Ap = mat ? P.cctxb : P.mctxb;
            const unsigned short* Bw = mat ? P.wc_bf : P.wm_bf;
            float* y = mat ? P.y_c : P.y_m;

            const unsigned short* ap = Ap + (m0 + l15) * 512 + quad * 8;
            const unsigned short* bp = Bw + (n0 + l15) * 512 + quad * 8;

            float4v acc0 = {0.f, 0.f, 0.f, 0.f};
            float4v acc1 = {0.f, 0.f, 0.f, 0.f};
#pragma unroll
            for (int k0 = 0; k0 < 512; k0 += 64) {
                short8 a0 = *(const short8*)(ap + k0);
                short8 b0 = *(const short8*)(bp + k0);
                short8 a1 = *(const short8*)(ap + k0 + 32);
                short8 b1 = *(const short8*)(bp + k0 + 32);
                acc0 = __builtin_amdgcn_mfma_f32_16x16x32_bf16(a0, b0, acc0, 0, 0, 0);
                acc1 = __builtin_amdgcn_mfma_f32_16x16x32_bf16(a1, b1, acc1, 0, 0, 0);
            }
#pragma unroll
            for (int r = 0; r < 4; ++r)
                y[(m0 + quad * 4 + r) * 512 + n0 + l15] = acc0[r] + acc1[r];
        }
    }
    gg.sync();

    // ---------------- P5b: bias + residual + LayerNorm (1 row/block) ----------
    {
        float* red8 = smemf;
        const int id = blk;                      // 0..511
        const int mat = id >> 8, row = id & 255;
        const float* yg = mat ? P.y_c : P.y_m;
        const float* bias = mat ? P.cov_b : P.mean_b;
        const float* res = mat ? P.x_c : P.x_m;
        const int base = row * 512;

        float y0 = yg[base + t] + bias[t] + res[base + t];
        float y1 = yg[base + 256 + t] + bias[256 + t] + res[base + 256 + t];
        float s = y0 + y1, ss = y0 * y0 + y1 * y1;
#pragma unroll
        for (int off = 32; off >= 1; off >>= 1) { s += __shfl_xor(s, off); ss += __shfl_xor(ss, off); }
        if ((t & 63) == 0) { red8[t >> 6] = s; red8[4 + (t >> 6)] = ss; }
        __syncthreads();
        float mu = (red8[0] + red8[1] + red8[2] + red8[3]) * (1.f / 512.f);
        float var = (red8[4] + red8[5] + red8[6] + red8[7]) * (1.f / 512.f) - mu * mu;
        float rstd = 1.f / sqrtf(var + 1e-12f);
        P.out[mat * 131072 + base + t] = (y0 - mu) * rstd * P.ln_w[t] + P.ln_b[t];
        P.out[mat * 131072 + base + 256 + t] = (y1 - mu) * rstd * P.ln_w[256 + t] + P.ln_b[256 + t];
    }
}

// ===========================================================================
// FALLBACK: the proven 6-kernel pipeline (used only if cooperative launch
// is rejected). Verbatim from R1.
// ===========================================================================

__global__ __launch_bounds__(256) void k_prep(
    const float* __restrict__ x_m, const float* __restrict__ b_m,
    const float* __restrict__ x_c, const float* __restrict__ b_c,
    const float* __restrict__ mean_w, const float* __restrict__ cov_w,
    const float* __restrict__ W_xm, const float* __restrict__ W_xc,
    const float* __restrict__ W_bm, const float* __restrict__ W_bc,
    const float* __restrict__ p_m, const float* __restrict__ bb_m,
    const float* __restrict__ Wq2, const float* __restrict__ Wk2,
    const float* __restrict__ Wq1, const float* __restrict__ Wk1,
    unsigned short* __restrict__ A_m, unsigned short* __restrict__ A_c,
    unsigned short* __restrict__ wm_bf, unsigned short* __restrict__ wc_bf,
    unsigned short* __restrict__ Wt,
    unsigned short* __restrict__ pm_bf, unsigned short* __restrict__ bbm_bf,
    unsigned short* __restrict__ w4_bf)
{
    __shared__ unsigned short tile4[4][32][33];
    const int t = threadIdx.x;
    const int blk = blockIdx.x;
    const int NBK = gridDim.x;

    for (int cid = blk * 256 + t; cid < 315392; cid += NBK * 256) {
        const float* srcp;
        unsigned short* dstp;
        if (cid < 262144) {
            int job = cid >> 16;
            int off = (cid & 65535) * 4;
            if (job <= 1) {
                int m = off >> 10, k = off & 1023;
                if (job == 0) { srcp = (k < 512) ? (x_m + m * 512 + k) : (b_m + m * 512 + k - 512); dstp = A_m + off; }
                else          { srcp = (k < 512) ? (x_c + m * 512 + k) : (b_c + m * 512 + k - 512); dstp = A_c + off; }
            } else if (job == 2) { srcp = mean_w + off; dstp = wm_bf + off; }
            else                 { srcp = cov_w + off;  dstp = wc_bf + off; }
        } else if (cid < 294912) {
            int off = (cid - 262144) * 4;
            srcp = p_m + off; dstp = pm_bf + off;
        } else if (cid < 299008) {
            int off = (cid - 294912) * 4;
            srcp = bb_m + off; dstp = bbm_bf + off;
        } else {
            int off = (cid - 299008) * 4;
            int seg = off >> 14;
            const float* Ws = (seg == 0) ? Wq2 : (seg == 1) ? Wk2 : (seg == 2) ? Wq1 : Wk1;
            srcp = Ws + (off & 16383); dstp = w4_bf + off;
        }
        float4 v = *(const float4*)srcp;
        ushort4v o4;
        o4.x = f2bf(v.x); o4.y = f2bf(v.y); o4.z = f2bf(v.z); o4.w = f2bf(v.w);
        *(ushort4v*)dstp = o4;
    }

    const int tx = t & 31, ty = t >> 5;
#pragma unroll
    for (int it = 0; it < 4; ++it) {
        int tid = blk + it * 768;
        int nt = tid & 15, kt = (tid >> 4) & 15, z = tid >> 8;
        int o = z >> 1, part = z & 1;
        const float* src;
        if (part == 0) src = (o < 3) ? (W_xm + o * 262144) : (W_xc + (o - 3) * 262144);
        else           src = (o < 3) ? (W_bm + o * 262144) : (W_bc + (o - 3) * 262144);
#pragma unroll
        for (int u = 0; u < 4; ++u)
            tile4[it][ty + u * 8][tx] = f2bf(src[(kt * 32 + ty + u * 8) * 512 + nt * 32 + tx]);
    }
    __syncthreads();
#pragma unroll
    for (int it = 0; it < 4; ++it) {
        int tid = blk + it * 768;
        int nt = tid & 15, kt = (tid >> 4) & 15, z = tid >> 8;
        int o = z >> 1, part = z & 1;
        unsigned short* dst = Wt + o * 524288 + part * 512;
#pragma unroll
        for (int u = 0; u < 4; ++u)
            dst[(nt * 32 + ty + u * 8) * 1024 + kt * 32 + tx] = tile4[it][tx][ty + u * 8];
    }
}

__global__ __launch_bounds__(256) void k_mm(
    const unsigned short* __restrict__ A_m, const unsigned short* __restrict__ A_c,
    const unsigned short* __restrict__ Wt,
    const unsigned short* __restrict__ pm_bf, const unsigned short* __restrict__ bbm_bf,
    const unsigned short* __restrict__ w4_bf,
    const float* __restrict__ bq2, const float* __restrict__ bk2,
    const float* __restrict__ bq1, const float* __restrict__ bk1,
    float* __restrict__ qkv, float* __restrict__ pq, float* __restrict__ pk,
    float* __restrict__ bbq, float* __restrict__ bbk)
{
    const int t = threadIdx.x;
    const int blk = blockIdx.x;
    const int sblk = (blk < 384) ? ((blk & 7) * 48 + (blk >> 3)) : blk;
    const int wid = sblk * 4 + (t >> 6);
    const int lane = t & 63;
    const int l15 = lane & 15, quad = lane >> 4;

    if (wid < 1536) {
        const int o = wid >> 8;
        const int rem = wid & 255;
        const int nt2 = rem & 15, mt = rem >> 4;
        const int m0 = mt * 16, n0 = nt2 * 32;

        const unsigned short* A = (o < 3) ? A_m : A_c;
        const unsigned short* ap  = A + (m0 + l15) * 1024 + quad * 8;
        const unsigned short* bpa = Wt + o * 524288 + (n0 + l15) * 1024 + quad * 8;
        const unsigned short* bpb = bpa + 16 * 1024;

        float4v accA0 = {0.f, 0.f, 0.f, 0.f};
        float4v accA1 = {0.f, 0.f, 0.f, 0.f};
        float4v accB0 = {0.f, 0.f, 0.f, 0.f};
        float4v accB1 = {0.f, 0.f, 0.f, 0.f};
#pragma unroll
        for (int k0 = 0; k0 < 1024; k0 += 64) {
            short8 a0 = *(const short8*)(ap + k0);
            short8 a1 = *(const short8*)(ap + k0 + 32);
            short8 b0a = *(const short8*)(bpa + k0);
            short8 b1a = *(const short8*)(bpa + k0 + 32);
            short8 b0b = *(const short8*)(bpb + k0);
            short8 b1b = *(const short8*)(bpb + k0 + 32);
            accA0 = __builtin_amdgcn_mfma_f32_16x16x32_bf16(a0, b0a, accA0, 0, 0, 0);
            accA1 = __builtin_amdgcn_mfma_f32_16x16x32_bf16(a1, b1a, accA1, 0, 0, 0);
            accB0 = __builtin_amdgcn_mfma_f32_16x16x32_bf16(a0, b0b, accB0, 0, 0, 0);
            accB1 = __builtin_amdgcn_mfma_f32_16x16x32_bf16(a1, b1b, accB1, 0, 0, 0);
        }
        float* dst = qkv + o * 131072;
#pragma unroll
        for (int r = 0; r < 4; ++r) {
            float va = accA0[r] + accA1[r];
            float vb = accB0[r] + accB1[r];
            if (o >= 3) { va = elu1(va); vb = elu1(vb); }
            dst[(m0 + quad * 4 + r) * 512 + n0 + l15] = va;
            dst[(m0 + quad * 4 + r) * 512 + n0 + 16 + l15] = vb;
        }
    } else {
        const unsigned short* Abf;
        const unsigned short* Wb;
        const float* bias;
        float* dst;
        int m0, n0, h;
        if (wid < 2560) {
            int lid = wid - 1536;
            int sel = lid >> 9;
            int r = lid & 511;
            h = r >> 7;
            int rem = r & 127;
            m0 = (rem >> 3) * 16; n0 = (rem & 7) * 16;
            Abf = pm_bf;
            Wb = w4_bf + sel * 16384;
            bias = sel ? bk2 : bq2;
            dst = sel ? pk : pq;
        } else {
            int lid = wid - 2560;
            int sel = lid >> 6;
            int r = lid & 63;
            h = r >> 4;
            int rem = r & 15;
            m0 = (rem >> 3) * 16; n0 = (rem & 7) * 16;
            Abf = bbm_bf;
            Wb = w4_bf + 32768 + sel * 16384;
            bias = sel ? bk1 : bq1;
            dst = sel ? bbk : bbq;
        }
        const unsigned short* ap = Abf + (m0 + l15) * 512 + h * 128 + quad * 8;
        const unsigned short* bp = Wb + (n0 + l15) * 128 + quad * 8;

        float4v acc0 = {0.f, 0.f, 0.f, 0.f};
        float4v acc1 = {0.f, 0.f, 0.f, 0.f};
#pragma unroll
        for (int k0 = 0; k0 < 128; k0 += 64) {
            short8 a0 = *(const short8*)(ap + k0);
            short8 b0 = *(const short8*)(bp + k0);
            short8 a1 = *(const short8*)(ap + k0 + 32);
            short8 b1 = *(const short8*)(bp + k0 + 32);
            acc0 = __builtin_amdgcn_mfma_f32_16x16x32_bf16(a0, b0, acc0, 0, 0, 0);
            acc1 = __builtin_amdgcn_mfma_f32_16x16x32_bf16(a1, b1, acc1, 0, 0, 0);
        }
        float bv = bias[n0 + l15];
#pragma unroll
        for (int r = 0; r < 4; ++r)
            dst[(m0 + quad * 4 + r) * 512 + h * 128 + n0 + l15] = acc0[r] + acc1[r] + bv;
    }
}

__global__ __launch_bounds__(128) void k_fuseK(
    const float* __restrict__ qkv, const float* __restrict__ pk,
    const float* __restrict__ bbk, const float* __restrict__ bb_c,
    const float* __restrict__ p_c, const int* __restrict__ b_seq,
    float* __restrict__ fKm, float* __restrict__ fKs)
{
    const int t = threadIdx.x;
    const int j = blockIdx.x, h = blockIdx.y, b = blockIdx.z;
    const int d = h * 128 + t;
    const float eps = 1e-24f;
    const int base = (b * S_ + j) * D_ + d;
    const int sj = b_seq[b * S_ + j];

    float m1 = qkv[M_ * D_ + base];
    float c1 = qkv[4 * M_ * D_ + base];
    float m3 = pk[base];
    float c3 = p_c[base];

    float p1 = 1.f / fmaxf(c1, eps);
    float p3 = 1.f / fmaxf(c3, eps);
    float mp13 = m1 * p1 + m3 * p3;

#pragma unroll
    for (int sv = 0; sv < 4; ++sv) {
        int idx = (b * 16 + sj * 4 + sv) * 512 + d;
        float m2 = bbk[idx];
        float c2 = bb_c[idx];
        float p2 = 1.f / fmaxf(c2, eps);
        float cc = 1.f / (p1 + p2 + p3);
        int o = (((b * H_ + h) * 4 + sv) * S_ + j) * 128 + t;
        fKm[o] = cc * (mp13 + m2 * p2);
        fKs[o] = sqrtf(fmaxf(cc, eps));
    }
}

__global__ __launch_bounds__(128) void k_attn3(
    const float* __restrict__ qkv, const float* __restrict__ pq,
    const float* __restrict__ bbq, const float* __restrict__ bb_c,
    const float* __restrict__ p_c, const int* __restrict__ b_seq,
    const float* __restrict__ fKm, const float* __restrict__ fKs,
    float* __restrict__ probs_out, unsigned short* __restrict__ mctxb,
    unsigned short* __restrict__ cctxb)
{
    const int t = threadIdx.x;
    const int blk = blockIdx.x;
    const int bh = blk & 7;
    const int i = blk >> 3;
    const int b = bh >> 2, h = bh & 3;
    const float eps = 1e-24f;

    __shared__ __attribute__((aligned(16))) float qm[4 * 132];
    __shared__ __attribute__((aligned(16))) float qs[4 * 132];
    __shared__ float red[4];
    __shared__ float pr[128], pr2[128];

    const int si = b_seq[b * S_ + i];
    const int sj = b_seq[b * S_ + t];

    {
        const int d = h * 128 + t;
        const int base = (b * S_ + i) * D_ + d;
        float m1 = qkv[base];
        float c1 = qkv[3 * M_ * D_ + base];
        float m3 = pq[base];
        float c3 = p_c[base];
        float p1 = 1.f / fmaxf(c1, eps);
        float p3 = 1.f / fmaxf(c3, eps);
        float mp13 = m1 * p1 + m3 * p3;
#pragma unroll
        for (int sv = 0; sv < 4; ++sv) {
            int idx = (b * 16 + sv * 4 + si) * 512 + d;
            float m2 = bbq[idx];
            float c2 = bb_c[idx];
            float p2 = 1.f / fmaxf(c2, eps);
            float cc = 1.f / (p1 + p2 + p3);
            qm[sv * 132 + t] = cc * (mp13 + m2 * p2);
            qs[sv * 132 + t] = sqrtf(fmaxf(cc, eps));
        }
    }
    __syncthreads();

    const int krow = (((b * H_ + h) * 4 + si) * S_ + t) * 128;
    const float4* kmp = (const float4*)(fKm + krow);
    const float4* ksp = (const float4*)(fKs + krow);

    float w2 = 0.f;
#pragma unroll 4
    for (int k4 = 0; k4 < 32; ++k4) {
        float4 km = kmp[k4];
        float4 ks = ksp[k4];
        float4 m = *(const float4*)&qm[sj * 132 + k4 * 4];
        float4 s = *(const float4*)&qs[sj * 132 + k4 * 4];
        float d0 = m.x - km.x, d1 = m.y - km.y, d2 = m.z - km.z, d3 = m.w - km.w;
        float e0 = s.x - ks.x, e1 = s.y - ks.y, e2 = s.z - ks.z, e3 = s.w - ks.w;
        w2 += d0 * d0 + d1 * d1 + d2 * d2 + d3 * d3
            + e0 * e0 + e1 * e1 + e2 * e2 + e3 * e3;
    }
    float score = -w2 * 0.08838834764831845f;

    float mx = score;
#pragma unroll
    for (int off = 32; off >= 1; off >>= 1) mx = fmaxf(mx, __shfl_xor(mx, off));
    if ((t & 63) == 0) red[t >> 6] = mx;
    __syncthreads();
    mx = fmaxf(red[0], red[1]);
    float e = __expf(score - mx);
    float sm = e;
#pragma unroll
    for (int off = 32; off >= 1; off >>= 1) sm += __shfl_xor(sm, off);
    if ((t & 63) == 0) red[2 + (t >> 6)] = sm;
    __syncthreads();
    float p = e / (red[2] + red[3]);

    probs_out[((b * H_ + h) * S_ + i) * S_ + t] = p;
    pr[t] = p;
    pr2[t] = p * p;
    __syncthreads();

    const float* v1 = qkv + 2 * M_ * D_ + (b * S_) * D_ + h * 128 + t;
    const float* v2 = qkv + 5 * M_ * D_ + (b * S_) * D_ + h * 128 + t;
    float am = 0.f, ac = 0.f;
#pragma unroll 8
    for (int j = 0; j < 128; ++j) {
        am = fmaf(pr[j], v1[j * D_], am);
        ac = fmaf(pr2[j], v2[j * D_], ac);
    }
    mctxb[(b * S_ + i) * D_ + h * 128 + t] = f2bf(am);
    cctxb[(b * S_ + i) * D_ + h * 128 + t] = f2bf(ac);
}

__global__ __launch_bounds__(256) void k_fin_mm(
    const unsigned short* __restrict__ mctxb, const unsigned short* __restrict__ cctxb,
    const unsigned short* __restrict__ wm_bf, const unsigned short* __restrict__ wc_bf,
    float* __restrict__ y_m, float* __restrict__ y_c)
{
    const int t = threadIdx.x;
    const int wid = blockIdx.x * 4 + (t >> 6);
    const int lane = t & 63;
    const int mat = wid >> 9;
    const int rem = wid & 511;
    const int nt = rem & 31, mt = rem >> 5;
    const int m0 = mt * 16, n0 = nt * 16;
    const int l15 = lane & 15, quad = lane >> 4;

    const unsigned short* A = mat ? cctxb : mctxb;
    const unsigned short* Bw = mat ? wc_bf : wm_bf;
    float* y = mat ? y_c : y_m;

    const unsigned short* ap = A + (m0 + l15) * 512 + quad * 8;
    const unsigned short* bp = Bw + (n0 + l15) * 512 + quad * 8;

    float4v acc0 = {0.f, 0.f, 0.f, 0.f};
    float4v acc1 = {0.f, 0.f, 0.f, 0.f};
#pragma unroll
    for (int k0 = 0; k0 < 512; k0 += 64) {
        short8 a0 = *(const short8*)(ap + k0);
        short8 b0 = *(const short8*)(bp + k0);
        short8 a1 = *(const short8*)(ap + k0 + 32);
        short8 b1 = *(const short8*)(bp + k0 + 32);
        acc0 = __builtin_amdgcn_mfma_f32_16x16x32_bf16(a0, b0, acc0, 0, 0, 0);
        acc1 = __builtin_amdgcn_mfma_f32_16x16x32_bf16(a1, b1, acc1, 0, 0, 0);
    }
#pragma unroll
    for (int r = 0; r < 4; ++r)
        y[(m0 + quad * 4 + r) * 512 + n0 + l15] = acc0[r] + acc1[r];
}

__global__ __launch_bounds__(256) void k_ln(
    const float* __restrict__ y_m, const float* __restrict__ y_c,
    const float* __restrict__ mean_b, const float* __restrict__ cov_b,
    const float* __restrict__ x_m, const float* __restrict__ x_c,
    const float* __restrict__ ln_w, const float* __restrict__ ln_b,
    float* __restrict__ out)
{
    const int t = threadIdx.x;
    const int id = blockIdx.x;
    const int mat = id >> 8, row = id & 255;
    const float* yg = mat ? y_c : y_m;
    const float* bias = mat ? cov_b : mean_b;
    const float* res = mat ? x_c : x_m;
    const int base = row * 512;

    __shared__ float red[8];

    float y0 = yg[base + t] + bias[t] + res[base + t];
    float y1 = yg[base + 256 + t] + bias[256 + t] + res[base + 256 + t];
    float s = y0 + y1, ss = y0 * y0 + y1 * y1;
#pragma unroll
    for (int off = 32; off >= 1; off >>= 1) { s += __shfl_xor(s, off); ss += __shfl_xor(ss, off); }
    if ((t & 63) == 0) { red[t >> 6] = s; red[4 + (t >> 6)] = ss; }
    __syncthreads();
    float mu = (red[0] + red[1] + red[2] + red[3]) * (1.f / 512.f);
    float var = (red[4] + red[5] + red[6] + red[7]) * (1.f / 512.f) - mu * mu;
    float rstd = 1.f / sqrtf(var + 1e-12f);
    out[mat * 131072 + base + t] = (y0 - mu) * rstd * ln_w[t] + ln_b[t];
    out[mat * 131072 + base + 256 + t] = (y1 - mu) * rstd * ln_w[256 + t] + ln_b[256 + t];
}

extern "C" void kernel_launch(void* const* d_in, const int* in_sizes, int n_in,
                              void* d_out, int out_size, void* d_ws, size_t ws_size,
                              hipStream_t stream) {
    (void)in_sizes; (void)n_in; (void)out_size; (void)ws_size;
    const float* x_m   = (const float*)d_in[0];
    const float* x_c   = (const float*)d_in[1];
    const float* b_m   = (const float*)d_in[2];
    const float* b_c   = (const float*)d_in[3];
    const float* bb_m  = (const float*)d_in[4];
    const float* bb_c  = (const float*)d_in[5];
    const float* p_m   = (const float*)d_in[6];
    const float* p_c   = (const float*)d_in[7];
    const float* W_xm  = (const float*)d_in[8];
    const float* W_xc  = (const float*)d_in[9];
    const float* W_bm  = (const float*)d_in[10];
    const float* W_bc  = (const float*)d_in[11];
    const float* Wq1_w = (const float*)d_in[12];
    const float* Wq1_b = (const float*)d_in[13];
    const float* Wq2_w = (const float*)d_in[14];
    const float* Wq2_b = (const float*)d_in[15];
    const float* Wk1_w = (const float*)d_in[16];
    const float* Wk1_b = (const float*)d_in[17];
    const float* Wk2_w = (const float*)d_in[18];
    const float* Wk2_b = (const float*)d_in[19];
    const float* mean_w = (const float*)d_in[20];
    const float* mean_b = (const float*)d_in[21];
    const float* cov_w  = (const float*)d_in[22];
    const float* cov_b  = (const float*)d_in[23];
    const float* ln_w   = (const float*)d_in[24];
    const float* ln_b   = (const float*)d_in[25];
    const int*   b_seq  = (const int*)d_in[26];

    float* ws = (float*)d_ws;
    float* qkv = ws;
    float* pq  = ws + 786432;
    float* pk  = ws + 917504;
    float* bbq = ws + 1048576;
    float* bbk = ws + 1064960;
    float* fKm = ws + 1081344;
    float* fKs = ws + 1605632;
    float* y_m = ws + 2129920;
    float* y_c = ws + 2260992;
    unsigned short* A_m    = (unsigned short*)(ws + 2392064);
    unsigned short* A_c    = (unsigned short*)(ws + 2523136);
    unsigned short* Wt     = (unsigned short*)(ws + 2654208);
    unsigned short* wm_bf  = (unsigned short*)(ws + 4227072);
    unsigned short* wc_bf  = (unsigned short*)(ws + 4358144);
    unsigned short* mctxb  = (unsigned short*)(ws + 4489216);
    unsigned short* cctxb  = (unsigned short*)(ws + 4554752);
    unsigned short* pm_bf  = (unsigned short*)(ws + 4620288);
    unsigned short* bbm_bf = (unsigned short*)(ws + 4685824);
    unsigned short* w4_bf  = (unsigned short*)(ws + 4694016);
    float* out = (float*)d_out;

    MegaArgs ma;
    ma.x_m = x_m; ma.x_c = x_c; ma.b_m = b_m; ma.b_c = b_c;
    ma.bb_m = bb_m; ma.bb_c = bb_c; ma.p_m = p_m; ma.p_c = p_c;
    ma.W_xm = W_xm; ma.W_xc = W_xc; ma.W_bm = W_bm; ma.W_bc = W_bc;
    ma.Wq1_b = Wq1_b; ma.Wq2_w = Wq2_w; ma.Wq2_b = Wq2_b;
    ma.Wk1_b = Wk1_b; ma.Wk2_w = Wk2_w; ma.Wk2_b = Wk2_b;
    ma.Wq1_w = Wq1_w; ma.Wk1_w = Wk1_w;
    ma.mean_w = mean_w; ma.mean_b = mean_b; ma.cov_w = cov_w; ma.cov_b = cov_b;
    ma.ln_w = ln_w; ma.ln_b = ln_b; ma.b_seq = b_seq;
    ma.qkv = qkv; ma.pq = pq; ma.pk = pk; ma.bbq = bbq; ma.bbk = bbk;
    ma.fKm = fKm; ma.fKs = fKs; ma.y_m = y_m; ma.y_c = y_c;
    ma.A_m = A_m; ma.A_c = A_c; ma.Wt = Wt; ma.wm_bf = wm_bf; ma.wc_bf = wc_bf;
    ma.mctxb = mctxb; ma.cctxb = cctxb; ma.pm_bf = pm_bf; ma.bbm_bf = bbm_bf;
    ma.w4_bf = w4_bf; ma.out = out;

    void* kargs[] = { (void*)&ma };
    hipError_t err = hipLaunchCooperativeKernel(
        reinterpret_cast<const void*>(&k_mega), dim3(512), dim3(256),
        kargs, 0, stream);

    if (err != hipSuccess) {
        (void)hipGetLastError();   // clear, fall back to the proven 6-kernel path
        k_prep<<<dim3(768), 256, 0, stream>>>(
            x_m, b_m, x_c, b_c, mean_w, cov_w, W_xm, W_xc, W_bm, W_bc,
            p_m, bb_m, Wq2_w, Wk2_w, Wq1_w, Wk1_w,
            A_m, A_c, wm_bf, wc_bf, Wt, pm_bf, bbm_bf, w4_bf);
        k_mm<<<dim3(672), 256, 0, stream>>>(
            A_m, A_c, Wt, pm_bf, bbm_bf, w4_bf,
            Wq2_b, Wk2_b, Wq1_b, Wk1_b,
            qkv, pq, pk, bbq, bbk);
        k_fuseK<<<dim3(128, 4, 2), 128, 0, stream>>>(
            qkv, pk, bbk, bb_c, p_c, b_seq, fKm, fKs);
        k_attn3<<<dim3(1024), 128, 0, stream>>>(
            qkv, pq, bbq, bb_c, p_c, b_seq, fKm, fKs, out + 262144, mctxb, cctxb);
        k_fin_mm<<<dim3(256), 256, 0, stream>>>(
            mctxb, cctxb, wm_bf, wc_bf, y_m, y_c);
        k_ln<<<dim3(512), 256, 0, stream>>>(
            y_m, y_c, mean_b, cov_b, x_m, x_c, ln_w, ln_b, out);
    }
}

// Round 4
// 187.420 us; speedup vs baseline: 2.5897x; 2.5897x over previous
//
#include <hip/hip_runtime.h>
#include <math.h>

#define B_ 2
#define S_ 128
#define H_ 4
#define DK_ 128
#define NB_ 4
#define D_ 512
#define M_ 256   // B_*S_

typedef __attribute__((ext_vector_type(8))) short short8;
typedef __attribute__((ext_vector_type(4))) float float4v;
typedef __attribute__((ext_vector_type(4))) unsigned short ushort4v;

__device__ __forceinline__ float elu1(float x) {
    return (x > 0.f) ? (x + 1.f) : __expf(x);
}

__device__ __forceinline__ unsigned short f2bf(float f) {
    unsigned u = __float_as_uint(f);
    unsigned r = (u + 0x7FFFu + ((u >> 16) & 1u)) >> 16;
    return (unsigned short)r;
}

// ---------------------------------------------------------------------------
// ws layout (float offsets) — identical to prior rounds (y_m/y_c now unused)
// ---------------------------------------------------------------------------

// ① prep: all bf16 conversions + projection-weight transpose. 768 blocks.
__global__ __launch_bounds__(256) void k_prep(
    const float* __restrict__ x_m, const float* __restrict__ b_m,
    const float* __restrict__ x_c, const float* __restrict__ b_c,
    const float* __restrict__ mean_w, const float* __restrict__ cov_w,
    const float* __restrict__ W_xm, const float* __restrict__ W_xc,
    const float* __restrict__ W_bm, const float* __restrict__ W_bc,
    const float* __restrict__ p_m, const float* __restrict__ bb_m,
    const float* __restrict__ Wq2, const float* __restrict__ Wk2,
    const float* __restrict__ Wq1, const float* __restrict__ Wk1,
    unsigned short* __restrict__ A_m, unsigned short* __restrict__ A_c,
    unsigned short* __restrict__ wm_bf, unsigned short* __restrict__ wc_bf,
    unsigned short* __restrict__ Wt,
    unsigned short* __restrict__ pm_bf, unsigned short* __restrict__ bbm_bf,
    unsigned short* __restrict__ w4_bf)
{
    __shared__ unsigned short tile4[4][32][33];
    const int t = threadIdx.x;
    const int blk = blockIdx.x;
    const int NBK = gridDim.x;   // must be 768 (3072 tiles = 4*768)

    for (int cid = blk * 256 + t; cid < 315392; cid += NBK * 256) {
        const float* srcp;
        unsigned short* dstp;
        if (cid < 262144) {
            int job = cid >> 16;
            int off = (cid & 65535) * 4;
            if (job <= 1) {
                int m = off >> 10, k = off & 1023;
                if (job == 0) { srcp = (k < 512) ? (x_m + m * 512 + k) : (b_m + m * 512 + k - 512); dstp = A_m + off; }
                else          { srcp = (k < 512) ? (x_c + m * 512 + k) : (b_c + m * 512 + k - 512); dstp = A_c + off; }
            } else if (job == 2) { srcp = mean_w + off; dstp = wm_bf + off; }
            else                 { srcp = cov_w + off;  dstp = wc_bf + off; }
        } else if (cid < 294912) {
            int off = (cid - 262144) * 4;
            srcp = p_m + off; dstp = pm_bf + off;
        } else if (cid < 299008) {
            int off = (cid - 294912) * 4;
            srcp = bb_m + off; dstp = bbm_bf + off;
        } else {
            int off = (cid - 299008) * 4;
            int seg = off >> 14;             // 16384 elems each
            const float* Ws = (seg == 0) ? Wq2 : (seg == 1) ? Wk2 : (seg == 2) ? Wq1 : Wk1;
            srcp = Ws + (off & 16383); dstp = w4_bf + off;
        }
        float4 v = *(const float4*)srcp;
        ushort4v o4;
        o4.x = f2bf(v.x); o4.y = f2bf(v.y); o4.z = f2bf(v.z); o4.w = f2bf(v.w);
        *(ushort4v*)dstp = o4;
    }

    const int tx = t & 31, ty = t >> 5;
#pragma unroll
    for (int it = 0; it < 4; ++it) {
        int tid = blk + it * 768;
        int nt = tid & 15, kt = (tid >> 4) & 15, z = tid >> 8;
        int o = z >> 1, part = z & 1;
        const float* src;
        if (part == 0) src = (o < 3) ? (W_xm + o * 262144) : (W_xc + (o - 3) * 262144);
        else           src = (o < 3) ? (W_bm + o * 262144) : (W_bc + (o - 3) * 262144);
#pragma unroll
        for (int u = 0; u < 4; ++u)
            tile4[it][ty + u * 8][tx] = f2bf(src[(kt * 32 + ty + u * 8) * 512 + nt * 32 + tx]);
    }
    __syncthreads();
#pragma unroll
    for (int it = 0; it < 4; ++it) {
        int tid = blk + it * 768;
        int nt = tid & 15, kt = (tid >> 4) & 15, z = tid >> 8;
        int o = z >> 1, part = z & 1;
        unsigned short* dst = Wt + o * 524288 + part * 512;
#pragma unroll
        for (int u = 0; u < 4; ++u)
            dst[(nt * 32 + ty + u * 8) * 1024 + kt * 32 + tx] = tile4[it][tx][ty + u * 8];
    }
}

// ② MFMA GEMM: qkv jobs wid 0..1535 (16x32 tile/wave), then pq/pk (K=128),
//    then bbq/bbk. XCD-affinity swizzle on the qkv block range.
__global__ __launch_bounds__(256) void k_mm(
    const unsigned short* __restrict__ A_m, const unsigned short* __restrict__ A_c,
    const unsigned short* __restrict__ Wt,
    const unsigned short* __restrict__ pm_bf, const unsigned short* __restrict__ bbm_bf,
    const unsigned short* __restrict__ w4_bf,
    const float* __restrict__ bq2, const float* __restrict__ bk2,
    const float* __restrict__ bq1, const float* __restrict__ bk1,
    float* __restrict__ qkv, float* __restrict__ pq, float* __restrict__ pk,
    float* __restrict__ bbq, float* __restrict__ bbk)
{
    const int t = threadIdx.x;
    const int blk = blockIdx.x;
    const int sblk = (blk < 384) ? ((blk & 7) * 48 + (blk >> 3)) : blk;
    const int wid = sblk * 4 + (t >> 6);
    const int lane = t & 63;
    const int l15 = lane & 15, quad = lane >> 4;

    if (wid < 1536) {
        const int o = wid >> 8;
        const int rem = wid & 255;
        const int nt2 = rem & 15, mt = rem >> 4;
        const int m0 = mt * 16, n0 = nt2 * 32;

        const unsigned short* A = (o < 3) ? A_m : A_c;
        const unsigned short* ap  = A + (m0 + l15) * 1024 + quad * 8;
        const unsigned short* bpa = Wt + o * 524288 + (n0 + l15) * 1024 + quad * 8;
        const unsigned short* bpb = bpa + 16 * 1024;

        float4v accA0 = {0.f, 0.f, 0.f, 0.f};
        float4v accA1 = {0.f, 0.f, 0.f, 0.f};
        float4v accB0 = {0.f, 0.f, 0.f, 0.f};
        float4v accB1 = {0.f, 0.f, 0.f, 0.f};
#pragma unroll
        for (int k0 = 0; k0 < 1024; k0 += 64) {
            short8 a0 = *(const short8*)(ap + k0);
            short8 a1 = *(const short8*)(ap + k0 + 32);
            short8 b0a = *(const short8*)(bpa + k0);
            short8 b1a = *(const short8*)(bpa + k0 + 32);
            short8 b0b = *(const short8*)(bpb + k0);
            short8 b1b = *(const short8*)(bpb + k0 + 32);
            accA0 = __builtin_amdgcn_mfma_f32_16x16x32_bf16(a0, b0a, accA0, 0, 0, 0);
            accA1 = __builtin_amdgcn_mfma_f32_16x16x32_bf16(a1, b1a, accA1, 0, 0, 0);
            accB0 = __builtin_amdgcn_mfma_f32_16x16x32_bf16(a0, b0b, accB0, 0, 0, 0);
            accB1 = __builtin_amdgcn_mfma_f32_16x16x32_bf16(a1, b1b, accB1, 0, 0, 0);
        }
        float* dst = qkv + o * 131072;
#pragma unroll
        for (int r = 0; r < 4; ++r) {
            float va = accA0[r] + accA1[r];
            float vb = accB0[r] + accB1[r];
            if (o >= 3) { va = elu1(va); vb = elu1(vb); }
            dst[(m0 + quad * 4 + r) * 512 + n0 + l15] = va;
            dst[(m0 + quad * 4 + r) * 512 + n0 + 16 + l15] = vb;
        }
    } else {
        const unsigned short* Abf;
        const unsigned short* Wb;
        const float* bias;
        float* dst;
        int m0, n0, h;
        if (wid < 2560) {
            int lid = wid - 1536;
            int sel = lid >> 9;              // 0=pq(Wq2), 1=pk(Wk2)
            int r = lid & 511;
            h = r >> 7;
            int rem = r & 127;
            m0 = (rem >> 3) * 16; n0 = (rem & 7) * 16;
            Abf = pm_bf;
            Wb = w4_bf + sel * 16384;
            bias = sel ? bk2 : bq2;
            dst = sel ? pk : pq;
        } else {
            int lid = wid - 2560;
            int sel = lid >> 6;              // 0=bbq(Wq1), 1=bbk(Wk1)
            int r = lid & 63;
            h = r >> 4;
            int rem = r & 15;
            m0 = (rem >> 3) * 16; n0 = (rem & 7) * 16;
            Abf = bbm_bf;
            Wb = w4_bf + 32768 + sel * 16384;
            bias = sel ? bk1 : bq1;
            dst = sel ? bbk : bbq;
        }
        const unsigned short* ap = Abf + (m0 + l15) * 512 + h * 128 + quad * 8;
        const unsigned short* bp = Wb + (n0 + l15) * 128 + quad * 8;

        float4v acc0 = {0.f, 0.f, 0.f, 0.f};
        float4v acc1 = {0.f, 0.f, 0.f, 0.f};
#pragma unroll
        for (int k0 = 0; k0 < 128; k0 += 64) {
            short8 a0 = *(const short8*)(ap + k0);
            short8 b0 = *(const short8*)(bp + k0);
            short8 a1 = *(const short8*)(ap + k0 + 32);
            short8 b1 = *(const short8*)(bp + k0 + 32);
            acc0 = __builtin_amdgcn_mfma_f32_16x16x32_bf16(a0, b0, acc0, 0, 0, 0);
            acc1 = __builtin_amdgcn_mfma_f32_16x16x32_bf16(a1, b1, acc1, 0, 0, 0);
        }
        float bv = bias[n0 + l15];
#pragma unroll
        for (int r = 0; r < 4; ++r)
            dst[(m0 + quad * 4 + r) * 512 + h * 128 + n0 + l15] = acc0[r] + acc1[r] + bv;
    }
}

// ③ fK precompute (tri-SAGP, K-side): S*NB work. Block (j,h,b), thread=dim.
__global__ __launch_bounds__(128) void k_fuseK(
    const float* __restrict__ qkv, const float* __restrict__ pk,
    const float* __restrict__ bbk, const float* __restrict__ bb_c,
    const float* __restrict__ p_c, const int* __restrict__ b_seq,
    float* __restrict__ fKm, float* __restrict__ fKs)
{
    const int t = threadIdx.x;
    const int j = blockIdx.x, h = blockIdx.y, b = blockIdx.z;
    const int d = h * 128 + t;
    const float eps = 1e-24f;
    const int base = (b * S_ + j) * D_ + d;
    const int sj = b_seq[b * S_ + j];

    float m1 = qkv[M_ * D_ + base];        // k1
    float c1 = qkv[4 * M_ * D_ + base];    // k2 (elu'd)
    float m3 = pk[base];
    float c3 = p_c[base];

    float p1 = 1.f / fmaxf(c1, eps);
    float p3 = 1.f / fmaxf(c3, eps);
    float mp13 = m1 * p1 + m3 * p3;

#pragma unroll
    for (int sv = 0; sv < 4; ++sv) {
        int idx = (b * 16 + sj * 4 + sv) * 512 + d;   // n1=seq[j], n2=sv(=si)
        float m2 = bbk[idx];
        float c2 = bb_c[idx];
        float p2 = 1.f / fmaxf(c2, eps);
        float cc = 1.f / (p1 + p2 + p3);
        int o = (((b * H_ + h) * 4 + sv) * S_ + j) * 128 + t;   // [B,H,NB,S,DK]
        fKm[o] = cc * (mp13 + m2 * p2);
        fKs[o] = sqrtf(fmaxf(cc, eps));
    }
}

// ④ attn: fQ inline + fK from ws; softmax; ctx. Flat grid 1024, XCD-pinned
//    per (b,h) (bh = blk&7, 8 (b,h) pairs on 8 XCDs).
__global__ __launch_bounds__(128) void k_attn3(
    const float* __restrict__ qkv, const float* __restrict__ pq,
    const float* __restrict__ bbq, const float* __restrict__ bb_c,
    const float* __restrict__ p_c, const int* __restrict__ b_seq,
    const float* __restrict__ fKm, const float* __restrict__ fKs,
    float* __restrict__ probs_out, unsigned short* __restrict__ mctxb,
    unsigned short* __restrict__ cctxb)
{
    const int t = threadIdx.x;
    const int blk = blockIdx.x;
    const int bh = blk & 7;
    const int i = blk >> 3;
    const int b = bh >> 2, h = bh & 3;
    const float eps = 1e-24f;

    __shared__ __attribute__((aligned(16))) float qm[4 * 132];
    __shared__ __attribute__((aligned(16))) float qs[4 * 132];
    __shared__ float red[4];
    __shared__ float pr[128], pr2[128];

    const int si = b_seq[b * S_ + i];
    const int sj = b_seq[b * S_ + t];

    {
        const int d = h * 128 + t;
        const int base = (b * S_ + i) * D_ + d;
        float m1 = qkv[base];                  // q1
        float c1 = qkv[3 * M_ * D_ + base];    // q2 (elu'd)
        float m3 = pq[base];
        float c3 = p_c[base];
        float p1 = 1.f / fmaxf(c1, eps);
        float p3 = 1.f / fmaxf(c3, eps);
        float mp13 = m1 * p1 + m3 * p3;
#pragma unroll
        for (int sv = 0; sv < 4; ++sv) {
            int idx = (b * 16 + sv * 4 + si) * 512 + d;   // n1=sv, n2=seq[i]
            float m2 = bbq[idx];
            float c2 = bb_c[idx];
            float p2 = 1.f / fmaxf(c2, eps);
            float cc = 1.f / (p1 + p2 + p3);
            qm[sv * 132 + t] = cc * (mp13 + m2 * p2);
            qs[sv * 132 + t] = sqrtf(fmaxf(cc, eps));
        }
    }
    __syncthreads();

    const int krow = (((b * H_ + h) * 4 + si) * S_ + t) * 128;
    const float4* kmp = (const float4*)(fKm + krow);
    const float4* ksp = (const float4*)(fKs + krow);

    float w2 = 0.f;
#pragma unroll 4
    for (int k4 = 0; k4 < 32; ++k4) {
        float4 km = kmp[k4];
        float4 ks = ksp[k4];
        float4 m = *(const float4*)&qm[sj * 132 + k4 * 4];
        float4 s = *(const float4*)&qs[sj * 132 + k4 * 4];
        float d0 = m.x - km.x, d1 = m.y - km.y, d2 = m.z - km.z, d3 = m.w - km.w;
        float e0 = s.x - ks.x, e1 = s.y - ks.y, e2 = s.z - ks.z, e3 = s.w - ks.w;
        w2 += d0 * d0 + d1 * d1 + d2 * d2 + d3 * d3
            + e0 * e0 + e1 * e1 + e2 * e2 + e3 * e3;
    }
    float score = -w2 * 0.08838834764831845f;   // 1/sqrt(128)

    float mx = score;
#pragma unroll
    for (int off = 32; off >= 1; off >>= 1) mx = fmaxf(mx, __shfl_xor(mx, off));
    if ((t & 63) == 0) red[t >> 6] = mx;
    __syncthreads();
    mx = fmaxf(red[0], red[1]);
    float e = __expf(score - mx);
    float sm = e;
#pragma unroll
    for (int off = 32; off >= 1; off >>= 1) sm += __shfl_xor(sm, off);
    if ((t & 63) == 0) red[2 + (t >> 6)] = sm;
    __syncthreads();
    float p = e / (red[2] + red[3]);

    probs_out[((b * H_ + h) * S_ + i) * S_ + t] = p;
    pr[t] = p;
    pr2[t] = p * p;
    __syncthreads();

    const float* v1 = qkv + 2 * M_ * D_ + (b * S_) * D_ + h * 128 + t;
    const float* v2 = qkv + 5 * M_ * D_ + (b * S_) * D_ + h * 128 + t;
    float am = 0.f, ac = 0.f;
#pragma unroll 8
    for (int j = 0; j < 128; ++j) {
        am = fmaf(pr[j], v1[j * D_], am);
        ac = fmaf(pr2[j], v2[j * D_], ac);
    }
    mctxb[(b * S_ + i) * D_ + h * 128 + t] = f2bf(am);
    cctxb[(b * S_ + i) * D_ + h * 128 + t] = f2bf(ac);
}

// ⑤ fused epilogue: MFMA GEMM (16-row stripe per block, via LDS) + bias +
//    residual + LayerNorm, direct store to out. 32 blocks x 256 threads.
//    Per-tile MFMA math identical to the old k_fin_mm (bitwise-same y);
//    LN formulas identical to old k_ln (reduction association differs only).
__global__ __launch_bounds__(256) void k_finln(
    const unsigned short* __restrict__ mctxb, const unsigned short* __restrict__ cctxb,
    const unsigned short* __restrict__ wm_bf, const unsigned short* __restrict__ wc_bf,
    const float* __restrict__ mean_b, const float* __restrict__ cov_b,
    const float* __restrict__ x_m, const float* __restrict__ x_c,
    const float* __restrict__ ln_w, const float* __restrict__ ln_b,
    float* __restrict__ out)
{
    const int t = threadIdx.x;
    const int blk = blockIdx.x;          // 0..31
    const int mat = blk >> 4;            // 0..1
    const int rg  = blk & 15;            // 16-row group
    const int m0 = rg * 16;
    const int w = t >> 6;                // wave 0..3
    const int lane = t & 63;
    const int l15 = lane & 15, quad = lane >> 4;

    __shared__ __attribute__((aligned(16))) float ytile[16][512];   // 32 KB

    const unsigned short* A  = mat ? cctxb : mctxb;
    const unsigned short* Bw = mat ? wc_bf : wm_bf;

    const unsigned short* ap = A + (m0 + l15) * 512 + quad * 8;

    // 8 n-tiles per wave: n0 = (w*8+j)*16, j=0..7  -> full 512-wide stripe
#pragma unroll 2
    for (int j = 0; j < 8; ++j) {
        const int n0 = (w * 8 + j) * 16;
        const unsigned short* bp = Bw + (n0 + l15) * 512 + quad * 8;
        float4v acc0 = {0.f, 0.f, 0.f, 0.f};
        float4v acc1 = {0.f, 0.f, 0.f, 0.f};
#pragma unroll
        for (int k0 = 0; k0 < 512; k0 += 64) {
            short8 a0 = *(const short8*)(ap + k0);
            short8 b0 = *(const short8*)(bp + k0);
            short8 a1 = *(const short8*)(ap + k0 + 32);
            short8 b1 = *(const short8*)(bp + k0 + 32);
            acc0 = __builtin_amdgcn_mfma_f32_16x16x32_bf16(a0, b0, acc0, 0, 0, 0);
            acc1 = __builtin_amdgcn_mfma_f32_16x16x32_bf16(a1, b1, acc1, 0, 0, 0);
        }
#pragma unroll
        for (int r = 0; r < 4; ++r)
            ytile[quad * 4 + r][n0 + l15] = acc0[r] + acc1[r];
    }
    __syncthreads();

    // LN: wave w handles local rows w*4 .. w*4+3; lane covers cols lane*8..+7
    const float* bias = mat ? cov_b : mean_b;
    const float* res  = mat ? x_c : x_m;
#pragma unroll
    for (int rr = 0; rr < 4; ++rr) {
        const int row = w * 4 + rr;
        const int base = (m0 + row) * 512;
        const int c0 = lane * 8;
        float v[8];
        float s = 0.f, ss = 0.f;
#pragma unroll
        for (int c = 0; c < 8; ++c) {
            float y = ytile[row][c0 + c] + bias[c0 + c] + res[base + c0 + c];
            v[c] = y; s += y; ss += y * y;
        }
#pragma unroll
        for (int off = 32; off >= 1; off >>= 1) {
            s += __shfl_xor(s, off);
            ss += __shfl_xor(ss, off);
        }
        float mu = s * (1.f / 512.f);
        float var = ss * (1.f / 512.f) - mu * mu;
        float rstd = 1.f / sqrtf(var + 1e-12f);
#pragma unroll
        for (int c = 0; c < 8; ++c)
            out[mat * 131072 + base + c0 + c] = (v[c] - mu) * rstd * ln_w[c0 + c] + ln_b[c0 + c];
    }
}

extern "C" void kernel_launch(void* const* d_in, const int* in_sizes, int n_in,
                              void* d_out, int out_size, void* d_ws, size_t ws_size,
                              hipStream_t stream) {
    (void)in_sizes; (void)n_in; (void)out_size; (void)ws_size;
    const float* x_m   = (const float*)d_in[0];
    const float* x_c   = (const float*)d_in[1];
    const float* b_m   = (const float*)d_in[2];
    const float* b_c   = (const float*)d_in[3];
    const float* bb_m  = (const float*)d_in[4];
    const float* bb_c  = (const float*)d_in[5];
    const float* p_m   = (const float*)d_in[6];
    const float* p_c   = (const float*)d_in[7];
    const float* W_xm  = (const float*)d_in[8];
    const float* W_xc  = (const float*)d_in[9];
    const float* W_bm  = (const float*)d_in[10];
    const float* W_bc  = (const float*)d_in[11];
    const float* Wq1_w = (const float*)d_in[12];
    const float* Wq1_b = (const float*)d_in[13];
    const float* Wq2_w = (const float*)d_in[14];
    const float* Wq2_b = (const float*)d_in[15];
    const float* Wk1_w = (const float*)d_in[16];
    const float* Wk1_b = (const float*)d_in[17];
    const float* Wk2_w = (const float*)d_in[18];
    const float* Wk2_b = (const float*)d_in[19];
    const float* mean_w = (const float*)d_in[20];
    const float* mean_b = (const float*)d_in[21];
    const float* cov_w  = (const float*)d_in[22];
    const float* cov_b  = (const float*)d_in[23];
    const float* ln_w   = (const float*)d_in[24];
    const float* ln_b   = (const float*)d_in[25];
    const int*   b_seq  = (const int*)d_in[26];

    float* ws = (float*)d_ws;
    float* qkv = ws;
    float* pq  = ws + 786432;
    float* pk  = ws + 917504;
    float* bbq = ws + 1048576;
    float* bbk = ws + 1064960;
    float* fKm = ws + 1081344;
    float* fKs = ws + 1605632;
    unsigned short* A_m    = (unsigned short*)(ws + 2392064);
    unsigned short* A_c    = (unsigned short*)(ws + 2523136);
    unsigned short* Wt     = (unsigned short*)(ws + 2654208);
    unsigned short* wm_bf  = (unsigned short*)(ws + 4227072);
    unsigned short* wc_bf  = (unsigned short*)(ws + 4358144);
    unsigned short* mctxb  = (unsigned short*)(ws + 4489216);
    unsigned short* cctxb  = (unsigned short*)(ws + 4554752);
    unsigned short* pm_bf  = (unsigned short*)(ws + 4620288);
    unsigned short* bbm_bf = (unsigned short*)(ws + 4685824);
    unsigned short* w4_bf  = (unsigned short*)(ws + 4694016);
    float* out = (float*)d_out;

    k_prep<<<dim3(768), 256, 0, stream>>>(
        x_m, b_m, x_c, b_c, mean_w, cov_w, W_xm, W_xc, W_bm, W_bc,
        p_m, bb_m, Wq2_w, Wk2_w, Wq1_w, Wk1_w,
        A_m, A_c, wm_bf, wc_bf, Wt, pm_bf, bbm_bf, w4_bf);
    k_mm<<<dim3(672), 256, 0, stream>>>(
        A_m, A_c, Wt, pm_bf, bbm_bf, w4_bf,
        Wq2_b, Wk2_b, Wq1_b, Wk1_b,
        qkv, pq, pk, bbq, bbk);
    k_fuseK<<<dim3(128, 4, 2), 128, 0, stream>>>(
        qkv, pk, bbk, bb_c, p_c, b_seq, fKm, fKs);
    k_attn3<<<dim3(1024), 128, 0, stream>>>(
        qkv, pq, bbq, bb_c, p_c, b_seq, fKm, fKs, out + 262144, mctxb, cctxb);
    k_finln<<<dim3(32), 256, 0, stream>>>(
        mctxb, cctxb, wm_bf, wc_bf, mean_b, cov_b, x_m, x_c, ln_w, ln_b, out);
}

// Round 5
// 175.504 us; speedup vs baseline: 2.7655x; 1.0679x over previous
//
#include <hip/hip_runtime.h>
#include <math.h>

#define B_ 2
#define S_ 128
#define H_ 4
#define DK_ 128
#define NB_ 4
#define D_ 512
#define M_ 256   // B_*S_

typedef __attribute__((ext_vector_type(8))) short short8;
typedef __attribute__((ext_vector_type(4))) float float4v;
typedef __attribute__((ext_vector_type(4))) unsigned short ushort4v;

__device__ __forceinline__ float elu1(float x) {
    return (x > 0.f) ? (x + 1.f) : __expf(x);
}

__device__ __forceinline__ unsigned short f2bf(float f) {
    unsigned u = __float_as_uint(f);
    unsigned r = (u + 0x7FFFu + ((u >> 16) & 1u)) >> 16;
    return (unsigned short)r;
}

// ---------------------------------------------------------------------------
// ws layout (float offsets)
//  qkv 786432@0 | pq 131072@786432 | pk 131072@917504 | bbq 16384@1048576
//  bbk 16384@1064960 | fKm 524288@1081344 | fKs 524288@1605632
//  y_m 131072@2129920 | y_c 131072@2260992 | A_m 131072@2392064
//  A_c 131072@2523136 | Wt 1572864@2654208 | wm_bf 131072@4227072
//  wc_bf 131072@4358144 | mctxb 65536@4489216 | cctxb 65536@4554752
//  pm_bf 65536@4620288 | bbm_bf 8192@4685824 | w4_bf 32768@4694016
// ---------------------------------------------------------------------------

// ① prep: all bf16 conversions + projection-weight transpose. 768 blocks.
__global__ __launch_bounds__(256) void k_prep(
    const float* __restrict__ x_m, const float* __restrict__ b_m,
    const float* __restrict__ x_c, const float* __restrict__ b_c,
    const float* __restrict__ mean_w, const float* __restrict__ cov_w,
    const float* __restrict__ W_xm, const float* __restrict__ W_xc,
    const float* __restrict__ W_bm, const float* __restrict__ W_bc,
    const float* __restrict__ p_m, const float* __restrict__ bb_m,
    const float* __restrict__ Wq2, const float* __restrict__ Wk2,
    const float* __restrict__ Wq1, const float* __restrict__ Wk1,
    unsigned short* __restrict__ A_m, unsigned short* __restrict__ A_c,
    unsigned short* __restrict__ wm_bf, unsigned short* __restrict__ wc_bf,
    unsigned short* __restrict__ Wt,
    unsigned short* __restrict__ pm_bf, unsigned short* __restrict__ bbm_bf,
    unsigned short* __restrict__ w4_bf)
{
    __shared__ unsigned short tile4[4][32][33];
    const int t = threadIdx.x;
    const int blk = blockIdx.x;
    const int NBK = gridDim.x;   // must be 768 (3072 tiles = 4*768)

    for (int cid = blk * 256 + t; cid < 315392; cid += NBK * 256) {
        const float* srcp;
        unsigned short* dstp;
        if (cid < 262144) {
            int job = cid >> 16;
            int off = (cid & 65535) * 4;
            if (job <= 1) {
                int m = off >> 10, k = off & 1023;
                if (job == 0) { srcp = (k < 512) ? (x_m + m * 512 + k) : (b_m + m * 512 + k - 512); dstp = A_m + off; }
                else          { srcp = (k < 512) ? (x_c + m * 512 + k) : (b_c + m * 512 + k - 512); dstp = A_c + off; }
            } else if (job == 2) { srcp = mean_w + off; dstp = wm_bf + off; }
            else                 { srcp = cov_w + off;  dstp = wc_bf + off; }
        } else if (cid < 294912) {
            int off = (cid - 262144) * 4;
            srcp = p_m + off; dstp = pm_bf + off;
        } else if (cid < 299008) {
            int off = (cid - 294912) * 4;
            srcp = bb_m + off; dstp = bbm_bf + off;
        } else {
            int off = (cid - 299008) * 4;
            int seg = off >> 14;             // 16384 elems each
            const float* Ws = (seg == 0) ? Wq2 : (seg == 1) ? Wk2 : (seg == 2) ? Wq1 : Wk1;
            srcp = Ws + (off & 16383); dstp = w4_bf + off;
        }
        float4 v = *(const float4*)srcp;
        ushort4v o4;
        o4.x = f2bf(v.x); o4.y = f2bf(v.y); o4.z = f2bf(v.z); o4.w = f2bf(v.w);
        *(ushort4v*)dstp = o4;
    }

    const int tx = t & 31, ty = t >> 5;
#pragma unroll
    for (int it = 0; it < 4; ++it) {
        int tid = blk + it * 768;
        int nt = tid & 15, kt = (tid >> 4) & 15, z = tid >> 8;
        int o = z >> 1, part = z & 1;
        const float* src;
        if (part == 0) src = (o < 3) ? (W_xm + o * 262144) : (W_xc + (o - 3) * 262144);
        else           src = (o < 3) ? (W_bm + o * 262144) : (W_bc + (o - 3) * 262144);
#pragma unroll
        for (int u = 0; u < 4; ++u)
            tile4[it][ty + u * 8][tx] = f2bf(src[(kt * 32 + ty + u * 8) * 512 + nt * 32 + tx]);
    }
    __syncthreads();
#pragma unroll
    for (int it = 0; it < 4; ++it) {
        int tid = blk + it * 768;
        int nt = tid & 15, kt = (tid >> 4) & 15, z = tid >> 8;
        int o = z >> 1, part = z & 1;
        unsigned short* dst = Wt + o * 524288 + part * 512;
#pragma unroll
        for (int u = 0; u < 4; ++u)
            dst[(nt * 32 + ty + u * 8) * 1024 + kt * 32 + tx] = tile4[it][tx][ty + u * 8];
    }
}

// ② MFMA GEMM: qkv jobs wid 0..1535 (16x32 tile/wave), then pq/pk (K=128),
//    then bbq/bbk. XCD-affinity swizzle on the qkv block range.
__global__ __launch_bounds__(256) void k_mm(
    const unsigned short* __restrict__ A_m, const unsigned short* __restrict__ A_c,
    const unsigned short* __restrict__ Wt,
    const unsigned short* __restrict__ pm_bf, const unsigned short* __restrict__ bbm_bf,
    const unsigned short* __restrict__ w4_bf,
    const float* __restrict__ bq2, const float* __restrict__ bk2,
    const float* __restrict__ bq1, const float* __restrict__ bk1,
    float* __restrict__ qkv, float* __restrict__ pq, float* __restrict__ pk,
    float* __restrict__ bbq, float* __restrict__ bbk)
{
    const int t = threadIdx.x;
    const int blk = blockIdx.x;
    const int sblk = (blk < 384) ? ((blk & 7) * 48 + (blk >> 3)) : blk;
    const int wid = sblk * 4 + (t >> 6);
    const int lane = t & 63;
    const int l15 = lane & 15, quad = lane >> 4;

    if (wid < 1536) {
        const int o = wid >> 8;
        const int rem = wid & 255;
        const int nt2 = rem & 15, mt = rem >> 4;
        const int m0 = mt * 16, n0 = nt2 * 32;

        const unsigned short* A = (o < 3) ? A_m : A_c;
        const unsigned short* ap  = A + (m0 + l15) * 1024 + quad * 8;
        const unsigned short* bpa = Wt + o * 524288 + (n0 + l15) * 1024 + quad * 8;
        const unsigned short* bpb = bpa + 16 * 1024;

        float4v accA0 = {0.f, 0.f, 0.f, 0.f};
        float4v accA1 = {0.f, 0.f, 0.f, 0.f};
        float4v accB0 = {0.f, 0.f, 0.f, 0.f};
        float4v accB1 = {0.f, 0.f, 0.f, 0.f};
#pragma unroll
        for (int k0 = 0; k0 < 1024; k0 += 64) {
            short8 a0 = *(const short8*)(ap + k0);
            short8 a1 = *(const short8*)(ap + k0 + 32);
            short8 b0a = *(const short8*)(bpa + k0);
            short8 b1a = *(const short8*)(bpa + k0 + 32);
            short8 b0b = *(const short8*)(bpb + k0);
            short8 b1b = *(const short8*)(bpb + k0 + 32);
            accA0 = __builtin_amdgcn_mfma_f32_16x16x32_bf16(a0, b0a, accA0, 0, 0, 0);
            accA1 = __builtin_amdgcn_mfma_f32_16x16x32_bf16(a1, b1a, accA1, 0, 0, 0);
            accB0 = __builtin_amdgcn_mfma_f32_16x16x32_bf16(a0, b0b, accB0, 0, 0, 0);
            accB1 = __builtin_amdgcn_mfma_f32_16x16x32_bf16(a1, b1b, accB1, 0, 0, 0);
        }
        float* dst = qkv + o * 131072;
#pragma unroll
        for (int r = 0; r < 4; ++r) {
            float va = accA0[r] + accA1[r];
            float vb = accB0[r] + accB1[r];
            if (o >= 3) { va = elu1(va); vb = elu1(vb); }
            dst[(m0 + quad * 4 + r) * 512 + n0 + l15] = va;
            dst[(m0 + quad * 4 + r) * 512 + n0 + 16 + l15] = vb;
        }
    } else {
        const unsigned short* Abf;
        const unsigned short* Wb;
        const float* bias;
        float* dst;
        int m0, n0, h;
        if (wid < 2560) {
            int lid = wid - 1536;
            int sel = lid >> 9;              // 0=pq(Wq2), 1=pk(Wk2)
            int r = lid & 511;
            h = r >> 7;
            int rem = r & 127;
            m0 = (rem >> 3) * 16; n0 = (rem & 7) * 16;
            Abf = pm_bf;
            Wb = w4_bf + sel * 16384;
            bias = sel ? bk2 : bq2;
            dst = sel ? pk : pq;
        } else {
            int lid = wid - 2560;
            int sel = lid >> 6;              // 0=bbq(Wq1), 1=bbk(Wk1)
            int r = lid & 63;
            h = r >> 4;
            int rem = r & 15;
            m0 = (rem >> 3) * 16; n0 = (rem & 7) * 16;
            Abf = bbm_bf;
            Wb = w4_bf + 32768 + sel * 16384;
            bias = sel ? bk1 : bq1;
            dst = sel ? bbk : bbq;
        }
        const unsigned short* ap = Abf + (m0 + l15) * 512 + h * 128 + quad * 8;
        const unsigned short* bp = Wb + (n0 + l15) * 128 + quad * 8;

        float4v acc0 = {0.f, 0.f, 0.f, 0.f};
        float4v acc1 = {0.f, 0.f, 0.f, 0.f};
#pragma unroll
        for (int k0 = 0; k0 < 128; k0 += 64) {
            short8 a0 = *(const short8*)(ap + k0);
            short8 b0 = *(const short8*)(bp + k0);
            short8 a1 = *(const short8*)(ap + k0 + 32);
            short8 b1 = *(const short8*)(bp + k0 + 32);
            acc0 = __builtin_amdgcn_mfma_f32_16x16x32_bf16(a0, b0, acc0, 0, 0, 0);
            acc1 = __builtin_amdgcn_mfma_f32_16x16x32_bf16(a1, b1, acc1, 0, 0, 0);
        }
        float bv = bias[n0 + l15];
#pragma unroll
        for (int r = 0; r < 4; ++r)
            dst[(m0 + quad * 4 + r) * 512 + h * 128 + n0 + l15] = acc0[r] + acc1[r] + bv;
    }
}

// ③ fK precompute (tri-SAGP, K-side): S*NB work. Block (j,h,b), thread=dim.
__global__ __launch_bounds__(128) void k_fuseK(
    const float* __restrict__ qkv, const float* __restrict__ pk,
    const float* __restrict__ bbk, const float* __restrict__ bb_c,
    const float* __restrict__ p_c, const int* __restrict__ b_seq,
    float* __restrict__ fKm, float* __restrict__ fKs)
{
    const int t = threadIdx.x;
    const int j = blockIdx.x, h = blockIdx.y, b = blockIdx.z;
    const int d = h * 128 + t;
    const float eps = 1e-24f;
    const int base = (b * S_ + j) * D_ + d;
    const int sj = b_seq[b * S_ + j];

    float m1 = qkv[M_ * D_ + base];        // k1
    float c1 = qkv[4 * M_ * D_ + base];    // k2 (elu'd)
    float m3 = pk[base];
    float c3 = p_c[base];

    float p1 = 1.f / fmaxf(c1, eps);
    float p3 = 1.f / fmaxf(c3, eps);
    float mp13 = m1 * p1 + m3 * p3;

#pragma unroll
    for (int sv = 0; sv < 4; ++sv) {
        int idx = (b * 16 + sj * 4 + sv) * 512 + d;   // n1=seq[j], n2=sv(=si)
        float m2 = bbk[idx];
        float c2 = bb_c[idx];
        float p2 = 1.f / fmaxf(c2, eps);
        float cc = 1.f / (p1 + p2 + p3);
        int o = (((b * H_ + h) * 4 + sv) * S_ + j) * 128 + t;   // [B,H,NB,S,DK]
        fKm[o] = cc * (mp13 + m2 * p2);
        fKs[o] = sqrtf(fmaxf(cc, eps));
    }
}

// ④ attn: fQ inline + fK from ws; softmax; ctx. Flat grid 1024, XCD-pinned
//    per (b,h) (bh = blk&7, 8 (b,h) pairs on 8 XCDs).
__global__ __launch_bounds__(128) void k_attn3(
    const float* __restrict__ qkv, const float* __restrict__ pq,
    const float* __restrict__ bbq, const float* __restrict__ bb_c,
    const float* __restrict__ p_c, const int* __restrict__ b_seq,
    const float* __restrict__ fKm, const float* __restrict__ fKs,
    float* __restrict__ probs_out, unsigned short* __restrict__ mctxb,
    unsigned short* __restrict__ cctxb)
{
    const int t = threadIdx.x;
    const int blk = blockIdx.x;
    const int bh = blk & 7;
    const int i = blk >> 3;
    const int b = bh >> 2, h = bh & 3;
    const float eps = 1e-24f;

    __shared__ __attribute__((aligned(16))) float qm[4 * 132];
    __shared__ __attribute__((aligned(16))) float qs[4 * 132];
    __shared__ float red[4];
    __shared__ float pr[128], pr2[128];

    const int si = b_seq[b * S_ + i];
    const int sj = b_seq[b * S_ + t];

    {
        const int d = h * 128 + t;
        const int base = (b * S_ + i) * D_ + d;
        float m1 = qkv[base];                  // q1
        float c1 = qkv[3 * M_ * D_ + base];    // q2 (elu'd)
        float m3 = pq[base];
        float c3 = p_c[base];
        float p1 = 1.f / fmaxf(c1, eps);
        float p3 = 1.f / fmaxf(c3, eps);
        float mp13 = m1 * p1 + m3 * p3;
#pragma unroll
        for (int sv = 0; sv < 4; ++sv) {
            int idx = (b * 16 + sv * 4 + si) * 512 + d;   // n1=sv, n2=seq[i]
            float m2 = bbq[idx];
            float c2 = bb_c[idx];
            float p2 = 1.f / fmaxf(c2, eps);
            float cc = 1.f / (p1 + p2 + p3);
            qm[sv * 132 + t] = cc * (mp13 + m2 * p2);
            qs[sv * 132 + t] = sqrtf(fmaxf(cc, eps));
        }
    }
    __syncthreads();

    const int krow = (((b * H_ + h) * 4 + si) * S_ + t) * 128;
    const float4* kmp = (const float4*)(fKm + krow);
    const float4* ksp = (const float4*)(fKs + krow);

    float w2 = 0.f;
#pragma unroll 4
    for (int k4 = 0; k4 < 32; ++k4) {
        float4 km = kmp[k4];
        float4 ks = ksp[k4];
        float4 m = *(const float4*)&qm[sj * 132 + k4 * 4];
        float4 s = *(const float4*)&qs[sj * 132 + k4 * 4];
        float d0 = m.x - km.x, d1 = m.y - km.y, d2 = m.z - km.z, d3 = m.w - km.w;
        float e0 = s.x - ks.x, e1 = s.y - ks.y, e2 = s.z - ks.z, e3 = s.w - ks.w;
        w2 += d0 * d0 + d1 * d1 + d2 * d2 + d3 * d3
            + e0 * e0 + e1 * e1 + e2 * e2 + e3 * e3;
    }
    float score = -w2 * 0.08838834764831845f;   // 1/sqrt(128)

    float mx = score;
#pragma unroll
    for (int off = 32; off >= 1; off >>= 1) mx = fmaxf(mx, __shfl_xor(mx, off));
    if ((t & 63) == 0) red[t >> 6] = mx;
    __syncthreads();
    mx = fmaxf(red[0], red[1]);
    float e = __expf(score - mx);
    float sm = e;
#pragma unroll
    for (int off = 32; off >= 1; off >>= 1) sm += __shfl_xor(sm, off);
    if ((t & 63) == 0) red[2 + (t >> 6)] = sm;
    __syncthreads();
    float p = e / (red[2] + red[3]);

    probs_out[((b * H_ + h) * S_ + i) * S_ + t] = p;
    pr[t] = p;
    pr2[t] = p * p;
    __syncthreads();

    const float* v1 = qkv + 2 * M_ * D_ + (b * S_) * D_ + h * 128 + t;
    const float* v2 = qkv + 5 * M_ * D_ + (b * S_) * D_ + h * 128 + t;
    float am = 0.f, ac = 0.f;
#pragma unroll 8
    for (int j = 0; j < 128; ++j) {
        am = fmaf(pr[j], v1[j * D_], am);
        ac = fmaf(pr2[j], v2[j * D_], ac);
    }
    mctxb[(b * S_ + i) * D_ + h * 128 + t] = f2bf(am);
    cctxb[(b * S_ + i) * D_ + h * 128 + t] = f2bf(ac);
}

// ⑤ epilogue MFMA GEMM: full K per wave, direct store. 1024 waves.
__global__ __launch_bounds__(256) void k_fin_mm(
    const unsigned short* __restrict__ mctxb, const unsigned short* __restrict__ cctxb,
    const unsigned short* __restrict__ wm_bf, const unsigned short* __restrict__ wc_bf,
    float* __restrict__ y_m, float* __restrict__ y_c)
{
    const int t = threadIdx.x;
    const int wid = blockIdx.x * 4 + (t >> 6);
    const int lane = t & 63;
    const int mat = wid >> 9;
    const int rem = wid & 511;
    const int nt = rem & 31, mt = rem >> 5;
    const int m0 = mt * 16, n0 = nt * 16;
    const int l15 = lane & 15, quad = lane >> 4;

    const unsigned short* A = mat ? cctxb : mctxb;
    const unsigned short* Bw = mat ? wc_bf : wm_bf;
    float* y = mat ? y_c : y_m;

    const unsigned short* ap = A + (m0 + l15) * 512 + quad * 8;
    const unsigned short* bp = Bw + (n0 + l15) * 512 + quad * 8;

    float4v acc0 = {0.f, 0.f, 0.f, 0.f};
    float4v acc1 = {0.f, 0.f, 0.f, 0.f};
#pragma unroll
    for (int k0 = 0; k0 < 512; k0 += 64) {
        short8 a0 = *(const short8*)(ap + k0);
        short8 b0 = *(const short8*)(bp + k0);
        short8 a1 = *(const short8*)(ap + k0 + 32);
        short8 b1 = *(const short8*)(bp + k0 + 32);
        acc0 = __builtin_amdgcn_mfma_f32_16x16x32_bf16(a0, b0, acc0, 0, 0, 0);
        acc1 = __builtin_amdgcn_mfma_f32_16x16x32_bf16(a1, b1, acc1, 0, 0, 0);
    }
#pragma unroll
    for (int r = 0; r < 4; ++r)
        y[(m0 + quad * 4 + r) * 512 + n0 + l15] = acc0[r] + acc1[r];
}

// ⑥ bias + residual + LayerNorm -> out. One block per output row (512 rows).
__global__ __launch_bounds__(256) void k_ln(
    const float* __restrict__ y_m, const float* __restrict__ y_c,
    const float* __restrict__ mean_b, const float* __restrict__ cov_b,
    const float* __restrict__ x_m, const float* __restrict__ x_c,
    const float* __restrict__ ln_w, const float* __restrict__ ln_b,
    float* __restrict__ out)
{
    const int t = threadIdx.x;
    const int id = blockIdx.x;
    const int mat = id >> 8, row = id & 255;
    const float* yg = mat ? y_c : y_m;
    const float* bias = mat ? cov_b : mean_b;
    const float* res = mat ? x_c : x_m;
    const int base = row * 512;

    __shared__ float red[8];

    float y0 = yg[base + t] + bias[t] + res[base + t];
    float y1 = yg[base + 256 + t] + bias[256 + t] + res[base + 256 + t];
    float s = y0 + y1, ss = y0 * y0 + y1 * y1;
#pragma unroll
    for (int off = 32; off >= 1; off >>= 1) { s += __shfl_xor(s, off); ss += __shfl_xor(ss, off); }
    if ((t & 63) == 0) { red[t >> 6] = s; red[4 + (t >> 6)] = ss; }
    __syncthreads();
    float mu = (red[0] + red[1] + red[2] + red[3]) * (1.f / 512.f);
    float var = (red[4] + red[5] + red[6] + red[7]) * (1.f / 512.f) - mu * mu;
    float rstd = 1.f / sqrtf(var + 1e-12f);
    out[mat * 131072 + base + t] = (y0 - mu) * rstd * ln_w[t] + ln_b[t];
    out[mat * 131072 + base + 256 + t] = (y1 - mu) * rstd * ln_w[256 + t] + ln_b[256 + t];
}

extern "C" void kernel_launch(void* const* d_in, const int* in_sizes, int n_in,
                              void* d_out, int out_size, void* d_ws, size_t ws_size,
                              hipStream_t stream) {
    (void)in_sizes; (void)n_in; (void)out_size; (void)ws_size;
    const float* x_m   = (const float*)d_in[0];
    const float* x_c   = (const float*)d_in[1];
    const float* b_m   = (const float*)d_in[2];
    const float* b_c   = (const float*)d_in[3];
    const float* bb_m  = (const float*)d_in[4];
    const float* bb_c  = (const float*)d_in[5];
    const float* p_m   = (const float*)d_in[6];
    const float* p_c   = (const float*)d_in[7];
    const float* W_xm  = (const float*)d_in[8];
    const float* W_xc  = (const float*)d_in[9];
    const float* W_bm  = (const float*)d_in[10];
    const float* W_bc  = (const float*)d_in[11];
    const float* Wq1_w = (const float*)d_in[12];
    const float* Wq1_b = (const float*)d_in[13];
    const float* Wq2_w = (const float*)d_in[14];
    const float* Wq2_b = (const float*)d_in[15];
    const float* Wk1_w = (const float*)d_in[16];
    const float* Wk1_b = (const float*)d_in[17];
    const float* Wk2_w = (const float*)d_in[18];
    const float* Wk2_b = (const float*)d_in[19];
    const float* mean_w = (const float*)d_in[20];
    const float* mean_b = (const float*)d_in[21];
    const float* cov_w  = (const float*)d_in[22];
    const float* cov_b  = (const float*)d_in[23];
    const float* ln_w   = (const float*)d_in[24];
    const float* ln_b   = (const float*)d_in[25];
    const int*   b_seq  = (const int*)d_in[26];

    float* ws = (float*)d_ws;
    float* qkv = ws;
    float* pq  = ws + 786432;
    float* pk  = ws + 917504;
    float* bbq = ws + 1048576;
    float* bbk = ws + 1064960;
    float* fKm = ws + 1081344;
    float* fKs = ws + 1605632;
    float* y_m = ws + 2129920;
    float* y_c = ws + 2260992;
    unsigned short* A_m    = (unsigned short*)(ws + 2392064);
    unsigned short* A_c    = (unsigned short*)(ws + 2523136);
    unsigned short* Wt     = (unsigned short*)(ws + 2654208);
    unsigned short* wm_bf  = (unsigned short*)(ws + 4227072);
    unsigned short* wc_bf  = (unsigned short*)(ws + 4358144);
    unsigned short* mctxb  = (unsigned short*)(ws + 4489216);
    unsigned short* cctxb  = (unsigned short*)(ws + 4554752);
    unsigned short* pm_bf  = (unsigned short*)(ws + 4620288);
    unsigned short* bbm_bf = (unsigned short*)(ws + 4685824);
    unsigned short* w4_bf  = (unsigned short*)(ws + 4694016);
    float* out = (float*)d_out;

    k_prep<<<dim3(768), 256, 0, stream>>>(
        x_m, b_m, x_c, b_c, mean_w, cov_w, W_xm, W_xc, W_bm, W_bc,
        p_m, bb_m, Wq2_w, Wk2_w, Wq1_w, Wk1_w,
        A_m, A_c, wm_bf, wc_bf, Wt, pm_bf, bbm_bf, w4_bf);
    k_mm<<<dim3(672), 256, 0, stream>>>(
        A_m, A_c, Wt, pm_bf, bbm_bf, w4_bf,
        Wq2_b, Wk2_b, Wq1_b, Wk1_b,
        qkv, pq, pk, bbq, bbk);
    k_fuseK<<<dim3(128, 4, 2), 128, 0, stream>>>(
        qkv, pk, bbk, bb_c, p_c, b_seq, fKm, fKs);
    k_attn3<<<dim3(1024), 128, 0, stream>>>(
        qkv, pq, bbq, bb_c, p_c, b_seq, fKm, fKs, out + 262144, mctxb, cctxb);
    k_fin_mm<<<dim3(256), 256, 0, stream>>>(
        mctxb, cctxb, wm_bf, wc_bf, y_m, y_c);
    k_ln<<<dim3(512), 256, 0, stream>>>(
        y_m, y_c, mean_b, cov_b, x_m, x_c, ln_w, ln_b, out);
}